// Round 8
// baseline (147.598 us; speedup 1.0000x reference)
//
#include <hip/hip_runtime.h>
#include <hip/hip_fp16.h>

#define BB 8
#define NN 200000
#define HH 480
#define WW 640
#define HWSZ (HH * WW)
#define BH 4                        // rows per slice
#define NSL (HH / BH)               // 120 slices
#define STRIDE 3584                 // arena slots per (b,slice); mean ~2083
#define AE ((size_t)BB * NSL * STRIDE)   // arena elements per tref

// dual-pass kernels
#define EPB2 1024
#define BPB2 ((NN + EPB2 - 1) / EPB2)    // 196
// sequential fallback kernels
#define EPB 2048
#define BPB ((NN + EPB - 1) / EPB)       // 98

// ---------------------------------------------------------------------------
// K0: flow interleave (f32x2 -> half2) fused with Charbonnier smoothness.
// ---------------------------------------------------------------------------
__global__ void __launch_bounds__(256) flow_prep(
        const float* __restrict__ flow, __half2* __restrict__ fxy,
        float* __restrict__ out) {
    const int total = BB * HWSZ;
    float s = 0.0f;
    for (int i = blockIdx.x * 256 + threadIdx.x; i < total;
         i += gridDim.x * 256) {
        int b = i / HWSZ, pix = i % HWSZ;
        const float* fb = flow + (size_t)b * 2 * HWSZ;
        float f0 = fb[pix], f1 = fb[HWSZ + pix];
        fxy[i] = __floats2half2_rn(f0, f1);
        int w = pix % WW, h = pix / WW;
        if (h < HH - 1) {
            float d0 = f0 - fb[pix + WW];
            float d1 = f1 - fb[HWSZ + pix + WW];
            s += sqrtf(d0 * d0 + 1e-6f) + sqrtf(d1 * d1 + 1e-6f);
        }
        if (w < WW - 1) {
            float d0 = f0 - fb[pix + 1];
            float d1 = f1 - fb[HWSZ + pix + 1];
            s += sqrtf(d0 * d0 + 1e-6f) + sqrtf(d1 * d1 + 1e-6f);
        }
    }
    #pragma unroll
    for (int off = 32; off > 0; off >>= 1)
        s += __shfl_down(s, off, 64);
    __shared__ float ls[4];
    int lane = threadIdx.x & 63, wid = threadIdx.x >> 6;
    if (lane == 0) ls[wid] = s;
    __syncthreads();
    if (threadIdx.x == 0)
        atomicAdd(out, ls[0] + ls[1] + ls[2] + ls[3]);
}

// ---------------------------------------------------------------------------
// K1-dual: warp each event for BOTH trefs in one pass (UNCHANGED from R6).
// payload: [qy:20 @38][qx:21 @17][pol:1 @16][qt:16 @0], coords (v+2)*2048.
// ---------------------------------------------------------------------------
__global__ void __launch_bounds__(256) warp_place_dual(
        const float4* __restrict__ ev, const __half2* __restrict__ fxy,
        unsigned int* __restrict__ counters,
        unsigned long long* __restrict__ arena) {
    __shared__ unsigned int h[2][NSL];
    __shared__ unsigned int bases[2][NSL];
    int b     = blockIdx.x & 7;            // XCD-affinity: batch b -> XCD b
    int chunk = blockIdx.x >> 3;
    if (threadIdx.x < 2 * NSL) h[threadIdx.x / NSL][threadIdx.x % NSL] = 0;
    __syncthreads();

    const float4*  evb = ev  + (size_t)b * NN;
    const __half2* fb  = fxy + (size_t)b * HWSZ;
    int base = chunk * EPB2;

    unsigned long long pay[2][4];
    unsigned short code[2][4];             // 0 invalid; else (s0+1) | dual<<8
    #pragma unroll
    for (int k = 0; k < 4; ++k) {
        code[0][k] = 0; code[1][k] = 0;
        int e = base + k * 256 + threadIdx.x;
        if (e < NN) {
            float4 E = evb[e];
            int gpix = (int)(E.y * 640.0f + E.z);
            float2 f = __half22float2(fb[gpix]);
            unsigned int pol = (E.w < 0.0f) ? 1u : 0u;
            #pragma unroll
            for (int t = 0; t < 2; ++t) {
                float tref = (t == 0) ? 1.0f : 0.0f;
                float dt = tref - E.x;
                float wy = fmaf(dt * f.y, 640.0f, E.y);   // flow_scaling=640
                float wx = fmaf(dt * f.x, 640.0f, E.z);
                if (wx >= -1.0f && wx < 640.0f && wy >= -2.0f && wy < 481.0f) {
                    int ity = (int)floorf(wy);
                    int r1 = ity + 1;
                    bool v0 = (ity >= 0) && (ity < HH);
                    bool v1 = (r1  >= 0) && (r1  < HH);
                    int s0 = -1; bool dual = false;
                    if (v0) { s0 = ity >> 2; dual = v1 && ((r1 >> 2) != s0); }
                    else if (v1) s0 = r1 >> 2;
                    if (s0 >= 0) {
                        code[t][k] = (unsigned short)((s0 + 1) | (dual ? 0x100 : 0));
                        float tw = (t == 0) ? E.x : (1.0f - E.x);
                        unsigned int qy = (unsigned int)((wy + 2.0f) * 2048.0f);
                        unsigned int qx = (unsigned int)((wx + 2.0f) * 2048.0f);
                        unsigned int qt = (unsigned int)fmaf(tw, 65535.0f, 0.5f);
                        pay[t][k] = ((unsigned long long)qy << 38)
                                  | ((unsigned long long)qx << 17)
                                  | ((unsigned long long)pol << 16)
                                  | (unsigned long long)qt;
                        atomicAdd(&h[t][s0], 1u);
                        if (dual) atomicAdd(&h[t][s0 + 1], 1u);
                    }
                }
            }
        }
    }
    __syncthreads();
    if (threadIdx.x < 2 * NSL) {           // 240 < 256
        int t = threadIdx.x / NSL, s = threadIdx.x % NSL;
        unsigned int c = h[t][s];
        bases[t][s] = c ? atomicAdd(&counters[(t * BB + b) * NSL + s], c) : 0u;
        h[t][s] = 0;                       // reuse as within-block cursor
    }
    __syncthreads();
    #pragma unroll
    for (int t = 0; t < 2; ++t) {
        unsigned long long* at = arena + (size_t)t * AE + (size_t)b * NSL * STRIDE;
        #pragma unroll
        for (int k = 0; k < 4; ++k) {
            unsigned int c = code[t][k];
            if (c) {
                int s = (int)(c & 0xff) - 1;
                unsigned int off = bases[t][s] + atomicAdd(&h[t][s], 1u);
                if (off < STRIDE) at[(size_t)s * STRIDE + off] = pay[t][k];
                if (c & 0x100) {
                    off = bases[t][s + 1] + atomicAdd(&h[t][s + 1], 1u);
                    if (off < STRIDE) at[(size_t)(s + 1) * STRIDE + off] = pay[t][k];
                }
            }
        }
    }
}

// ---------------------------------------------------------------------------
// Accumulate one (b,slice,tref) bucket: vector-zero LDS, 4-deep pipelined
// payload loads (OOB -> 0, which decodes to fully-clipped no-op), ds_pk_add
// accumulate, skip-zero ratio reduce with v_rcp, one global atomic.
// ---------------------------------------------------------------------------
__device__ __forceinline__ void accum_bucket(
        const unsigned long long* __restrict__ cell, unsigned int cnt, int r0,
        __half2* __restrict__ acc, float* __restrict__ ls,
        float* __restrict__ out) {
    uint4* az = (uint4*)acc;               // 1280 x uint4 = 20 KB
    for (int i = threadIdx.x; i < (BH * WW * 2) / 4; i += 512)
        az[i] = make_uint4(0u, 0u, 0u, 0u);
    __syncthreads();

    for (unsigned int base = 0; base < cnt; base += 4u * 512u) {
        unsigned long long p[4];
        #pragma unroll
        for (int k = 0; k < 4; ++k) {
            unsigned int idx = base + (unsigned int)k * 512u + threadIdx.x;
            p[k] = (idx < cnt) ? cell[idx] : 0ull;   // 4 independent loads
        }
        #pragma unroll
        for (int k = 0; k < 4; ++k) {
            unsigned long long q = p[k];
            if (q == 0ull) continue;       // padding: no-op
            float tw = (float)(unsigned int)(q & 0xFFFFu) * (1.0f / 65535.0f);
            int  pol = (int)((q >> 16) & 1u);
            float wx = (float)(unsigned int)((q >> 17) & 0x1FFFFFu) * (1.0f / 2048.0f) - 2.0f;
            float wy = (float)(unsigned int)((q >> 38) & 0xFFFFFu)  * (1.0f / 2048.0f) - 2.0f;
            float fy = floorf(wy), fx = floorf(wx);
            float ry = wy - fy,    rx = wx - fx;
            int ity = (int)fy, ilx = (int)fx;
            #pragma unroll
            for (int dy = 0; dy < 2; ++dy) {
                int r = ity + dy;
                if (r < r0 || r >= r0 + BH) continue;   // clip rows to slice
                float wyw = dy ? ry : 1.0f - ry;
                #pragma unroll
                for (int dx = 0; dx < 2; ++dx) {
                    int ix = ilx + dx;
                    if (ix < 0 || ix >= WW) continue;
                    float wgt = wyw * (dx ? rx : 1.0f - rx);
                    int a = ((r - r0) * WW + ix) * 2 + pol;
                    unsafeAtomicAdd(&acc[a], __floats2half2_rn(wgt, wgt * tw));
                }
            }
        }
    }
    __syncthreads();

    float sum = 0.0f;
    const uint2* av = (const uint2*)acc;   // 2560 x uint2
    for (int i = threadIdx.x; i < (BH * WW * 2) / 2; i += 512) {
        uint2 v = av[i];
        if (v.x) {
            float2 c = __half22float2(*(const __half2*)&v.x);
            float r = c.y * __builtin_amdgcn_rcpf(c.x + 1e-9f);
            sum += r * r;
        }
        if (v.y) {
            float2 c = __half22float2(*(const __half2*)&v.y);
            float r = c.y * __builtin_amdgcn_rcpf(c.x + 1e-9f);
            sum += r * r;
        }
    }
    #pragma unroll
    for (int off = 32; off > 0; off >>= 1)
        sum += __shfl_down(sum, off, 64);
    int lane = threadIdx.x & 63, wid = threadIdx.x >> 6;
    if (lane == 0) ls[wid] = sum;
    __syncthreads();
    if (threadIdx.x == 0) {
        float tot = 0.0f;
        #pragma unroll
        for (int k = 0; k < 8; ++k) tot += ls[k];
        atomicAdd(out, tot);
    }
}

// K2-fused: one block per (b,slice); both trefs serially in-block.
// Grid 960 @ 4 blocks/CU = one dispatch round (no tail).
__global__ void __launch_bounds__(512) slice_accum_fused(
        const unsigned long long* __restrict__ arena,
        const unsigned int* __restrict__ counters, float* __restrict__ out) {
    __shared__ __half2 acc[BH * WW * 2];   // 20 KB
    __shared__ float ls[8];
    int b = blockIdx.x & 7;                // XCD-affinity
    int s = blockIdx.x >> 3;
    #pragma unroll
    for (int t = 0; t < 2; ++t) {
        unsigned int cnt = counters[(t * BB + b) * NSL + s];
        if (cnt > STRIDE) cnt = STRIDE;
        const unsigned long long* cell =
            arena + (size_t)t * AE + ((size_t)(b * NSL + s)) * STRIDE;
        accum_bucket(cell, cnt, s * BH, acc, ls, out);
        __syncthreads();                   // protect acc reuse across trefs
    }
}

// ---------------------------------------------------------------------------
// Sequential fallback (only if ws too small for dual; shares accum_bucket).
// ---------------------------------------------------------------------------
__global__ void __launch_bounds__(256) warp_place(
        const float4* __restrict__ ev, const __half2* __restrict__ fxy,
        unsigned int* __restrict__ counters,
        unsigned long long* __restrict__ arena, float tref) {
    __shared__ unsigned int h[NSL];
    __shared__ unsigned int bases[NSL];
    int b     = blockIdx.x & 7;
    int chunk = blockIdx.x >> 3;
    for (int i = threadIdx.x; i < NSL; i += 256) h[i] = 0;
    __syncthreads();

    const float4*  evb = ev  + (size_t)b * NN;
    const __half2* fb  = fxy + (size_t)b * HWSZ;
    int base = chunk * EPB;

    unsigned long long pay[8];
    int code[8];
    #pragma unroll
    for (int k = 0; k < 8; ++k) {
        code[k] = 0;
        int e = base + k * 256 + threadIdx.x;
        if (e < NN) {
            float4 E = evb[e];
            int gpix = (int)(E.y * 640.0f + E.z);
            float2 f = __half22float2(fb[gpix]);
            float dt = tref - E.x;
            float wy = fmaf(dt * f.y, 640.0f, E.y);
            float wx = fmaf(dt * f.x, 640.0f, E.z);
            if (wx >= -1.0f && wx < 640.0f && wy >= -2.0f && wy < 481.0f) {
                int ity = (int)floorf(wy);
                int r1 = ity + 1;
                bool v0 = (ity >= 0) && (ity < HH);
                bool v1 = (r1  >= 0) && (r1  < HH);
                int s0 = -1; bool dual = false;
                if (v0) { s0 = ity >> 2; dual = v1 && ((r1 >> 2) != s0); }
                else if (v1) s0 = r1 >> 2;
                if (s0 >= 0) {
                    code[k] = (s0 + 1) | (dual ? 0x100 : 0);
                    float tw = (tref == 1.0f) ? E.x : (1.0f - E.x);
                    unsigned int pol = (E.w < 0.0f) ? 1u : 0u;
                    unsigned int qy = (unsigned int)((wy + 2.0f) * 2048.0f);
                    unsigned int qx = (unsigned int)((wx + 2.0f) * 2048.0f);
                    unsigned int qt = (unsigned int)fmaf(tw, 65535.0f, 0.5f);
                    pay[k] = ((unsigned long long)qy << 38)
                           | ((unsigned long long)qx << 17)
                           | ((unsigned long long)pol << 16)
                           | (unsigned long long)qt;
                    atomicAdd(&h[s0], 1u);
                    if (dual) atomicAdd(&h[s0 + 1], 1u);
                }
            }
        }
    }
    __syncthreads();
    for (int s = threadIdx.x; s < NSL; s += 256) {
        unsigned int c = h[s];
        bases[s] = c ? atomicAdd(&counters[b * NSL + s], c) : 0u;
        h[s] = 0;
    }
    __syncthreads();
    #pragma unroll
    for (int k = 0; k < 8; ++k) {
        if (code[k]) {
            int s = (code[k] & 0xff) - 1;
            unsigned int off = bases[s] + atomicAdd(&h[s], 1u);
            if (off < STRIDE)
                arena[((size_t)(b * NSL + s)) * STRIDE + off] = pay[k];
            if (code[k] & 0x100) {
                off = bases[s + 1] + atomicAdd(&h[s + 1], 1u);
                if (off < STRIDE)
                    arena[((size_t)(b * NSL + s + 1)) * STRIDE + off] = pay[k];
            }
        }
    }
}

__global__ void __launch_bounds__(512) slice_accum_single(
        const unsigned long long* __restrict__ arena,
        const unsigned int* __restrict__ counters, float* __restrict__ out) {
    __shared__ __half2 acc[BH * WW * 2];
    __shared__ float ls[8];
    int b = blockIdx.x & 7;
    int s = blockIdx.x >> 3;
    unsigned int cnt = counters[b * NSL + s];
    if (cnt > STRIDE) cnt = STRIDE;
    const unsigned long long* cell = arena + ((size_t)(b * NSL + s)) * STRIDE;
    accum_bucket(cell, cnt, s * BH, acc, ls, out);
}

extern "C" void kernel_launch(void* const* d_in, const int* in_sizes, int n_in,
                              void* d_out, int out_size, void* d_ws, size_t ws_size,
                              hipStream_t stream) {
    const float*  flow = (const float*)d_in[0];   // [B,2,H,W]
    const float4* ev   = (const float4*)d_in[1];  // [B,N,4]
    float* out = (float*)d_out;

    const size_t arena_bytes = AE * sizeof(unsigned long long);     // 27.5 MB
    const size_t fxy_bytes   = (size_t)BB * HWSZ * sizeof(__half2); // 9.83 MB
    const size_t need_dual   = 2 * arena_bytes + fxy_bytes + 2 * BB * NSL * 4;
    const bool dual = (ws_size >= need_dual);

    unsigned long long* arena = (unsigned long long*)d_ws;
    __half2* fxy = (__half2*)((char*)d_ws + (dual ? 2 : 1) * arena_bytes);
    unsigned int* counters = (unsigned int*)((char*)fxy + fxy_bytes);

    hipMemsetAsync(out, 0, sizeof(float), stream);
    flow_prep<<<1024, 256, 0, stream>>>(flow, fxy, out);

    if (dual) {
        hipMemsetAsync(counters, 0, 2 * BB * NSL * sizeof(unsigned int), stream);
        warp_place_dual<<<8 * BPB2, 256, 0, stream>>>(ev, fxy, counters, arena);
        slice_accum_fused<<<8 * NSL, 512, 0, stream>>>(arena, counters, out);
    } else {
        for (int t = 0; t < 2; ++t) {
            float tref = (t == 0) ? 1.0f : 0.0f;
            hipMemsetAsync(counters, 0, BB * NSL * sizeof(unsigned int), stream);
            warp_place<<<8 * BPB, 256, 0, stream>>>(ev, fxy, counters, arena, tref);
            slice_accum_single<<<8 * NSL, 512, 0, stream>>>(arena, counters, out);
        }
    }
}

// Round 10
// 145.013 us; speedup vs baseline: 1.0178x; 1.0178x over previous
//
#include <hip/hip_runtime.h>
#include <hip/hip_fp16.h>

#define BB 8
#define NN 200000
#define HH 480
#define WW 640
#define HWSZ (HH * WW)
#define BH 8                        // rows per slice
#define NSL (HH / BH)               // 60 slices
#define STRIDE 4608                 // u64 slots per (b,slice); mean ~3750
#define AE ((size_t)BB * NSL * STRIDE)   // arena u64 elements per tref

#define EPB2 1024
#define BPB2 ((NN + EPB2 - 1) / EPB2)    // 196

// ---------------------------------------------------------------------------
// K0: flow interleave (f32x2 -> half2) fused with Charbonnier smoothness.
// ---------------------------------------------------------------------------
__global__ void __launch_bounds__(256) flow_prep(
        const float* __restrict__ flow, __half2* __restrict__ fxy,
        float* __restrict__ out) {
    const int total = BB * HWSZ;
    float s = 0.0f;
    for (int i = blockIdx.x * 256 + threadIdx.x; i < total;
         i += gridDim.x * 256) {
        int b = i / HWSZ, pix = i % HWSZ;
        const float* fb = flow + (size_t)b * 2 * HWSZ;
        float f0 = fb[pix], f1 = fb[HWSZ + pix];
        fxy[i] = __floats2half2_rn(f0, f1);
        int w = pix % WW, h = pix / WW;
        if (h < HH - 1) {
            float d0 = f0 - fb[pix + WW];
            float d1 = f1 - fb[HWSZ + pix + WW];
            s += sqrtf(d0 * d0 + 1e-6f) + sqrtf(d1 * d1 + 1e-6f);
        }
        if (w < WW - 1) {
            float d0 = f0 - fb[pix + 1];
            float d1 = f1 - fb[HWSZ + pix + 1];
            s += sqrtf(d0 * d0 + 1e-6f) + sqrtf(d1 * d1 + 1e-6f);
        }
    }
    #pragma unroll
    for (int off = 32; off > 0; off >>= 1)
        s += __shfl_down(s, off, 64);
    __shared__ float ls[4];
    int lane = threadIdx.x & 63, wid = threadIdx.x >> 6;
    if (lane == 0) ls[wid] = s;
    __syncthreads();
    if (threadIdx.x == 0)
        atomicAdd(out, ls[0] + ls[1] + ls[2] + ls[3]);
}

// ---------------------------------------------------------------------------
// K1: warp each event for BOTH trefs; per-tref LDS hist; one global atomicAdd
// per touched (tref,slice) to reserve a range; 8B packed payloads (PROVEN R7
// encoding): [qy:20 @38][qx:21 @17][pol:1 @16][qt:16 @0], coords (v+2)*2048.
// Same payload goes to both buckets of a straddling event (absolute coords).
// ---------------------------------------------------------------------------
__global__ void __launch_bounds__(256) warp_place_dual(
        const float4* __restrict__ ev, const __half2* __restrict__ fxy,
        unsigned int* __restrict__ counters,
        unsigned long long* __restrict__ arena) {
    __shared__ unsigned int h[2][NSL];
    __shared__ unsigned int bases[2][NSL];
    int b     = blockIdx.x & 7;            // XCD-affinity: batch b -> XCD b
    int chunk = blockIdx.x >> 3;
    if (threadIdx.x < 2 * NSL) h[threadIdx.x / NSL][threadIdx.x % NSL] = 0;
    __syncthreads();

    const float4*  evb = ev  + (size_t)b * NN;
    const __half2* fb  = fxy + (size_t)b * HWSZ;
    int base = chunk * EPB2;

    unsigned long long pay[2][4];
    unsigned short code[2][4];             // 0 invalid; else (s0+1) | dual<<8
    #pragma unroll
    for (int k = 0; k < 4; ++k) {
        code[0][k] = 0; code[1][k] = 0;
        int e = base + k * 256 + threadIdx.x;
        if (e < NN) {
            float4 E = evb[e];
            int gpix = (int)(E.y * 640.0f + E.z);
            float2 f = __half22float2(fb[gpix]);
            unsigned int pol = (E.w < 0.0f) ? 1u : 0u;
            #pragma unroll
            for (int t = 0; t < 2; ++t) {
                float tref = (t == 0) ? 1.0f : 0.0f;
                float dt = tref - E.x;
                float wy = fmaf(dt * f.y, 640.0f, E.y);   // flow_scaling=640
                float wx = fmaf(dt * f.x, 640.0f, E.z);
                if (wx >= -1.0f && wx < 640.0f && wy >= -2.0f && wy < 481.0f) {
                    int ity = (int)floorf(wy);
                    int r1 = ity + 1;
                    bool v0 = (ity >= 0) && (ity < HH);
                    bool v1 = (r1  >= 0) && (r1  < HH);
                    int s0 = -1; bool dual = false;
                    if (v0) { s0 = ity >> 3; dual = v1 && ((r1 >> 3) != s0); }
                    else if (v1) s0 = r1 >> 3;
                    if (s0 >= 0) {
                        code[t][k] = (unsigned short)((s0 + 1) | (dual ? 0x100 : 0));
                        float tw = (t == 0) ? E.x : (1.0f - E.x);
                        unsigned int qy = (unsigned int)((wy + 2.0f) * 2048.0f);
                        unsigned int qx = (unsigned int)((wx + 2.0f) * 2048.0f);
                        unsigned int qt = (unsigned int)fmaf(tw, 65535.0f, 0.5f);
                        pay[t][k] = ((unsigned long long)qy << 38)
                                  | ((unsigned long long)qx << 17)
                                  | ((unsigned long long)pol << 16)
                                  | (unsigned long long)qt;
                        atomicAdd(&h[t][s0], 1u);
                        if (dual) atomicAdd(&h[t][s0 + 1], 1u);
                    }
                }
            }
        }
    }
    __syncthreads();
    if (threadIdx.x < 2 * NSL) {           // 120 < 256
        int t = threadIdx.x / NSL, s = threadIdx.x % NSL;
        unsigned int c = h[t][s];
        bases[t][s] = c ? atomicAdd(&counters[(t * BB + b) * NSL + s], c) : 0u;
        h[t][s] = 0;                       // reuse as within-block cursor
    }
    __syncthreads();
    #pragma unroll
    for (int t = 0; t < 2; ++t) {
        unsigned long long* at = arena + (size_t)t * AE + (size_t)b * NSL * STRIDE;
        #pragma unroll
        for (int k = 0; k < 4; ++k) {
            unsigned int c = code[t][k];
            if (c) {
                int s = (int)(c & 0xff) - 1;
                unsigned long long p = pay[t][k];
                unsigned int off = bases[t][s] + atomicAdd(&h[t][s], 1u);
                if (off < STRIDE) at[(size_t)s * STRIDE + off] = p;
                if (c & 0x100) {
                    off = bases[t][s + 1] + atomicAdd(&h[t][s + 1], 1u);
                    if (off < STRIDE) at[(size_t)(s + 1) * STRIDE + off] = p;
                }
            }
        }
    }
}

// ---------------------------------------------------------------------------
// K2: one block (1024 thr) per (b,slice); both trefs serial in-block.
// ulonglong2 arena reads (16B/lane = 2 events), LDS half2 accumulate via
// ds_pk_add_f16, skip-zero ratio reduce with v_rcp, one atomic per bucket.
// Grid 480 @ 2 blocks/CU (40KB LDS) = 32 waves/CU.
// ---------------------------------------------------------------------------
__global__ void __launch_bounds__(1024) slice_accum_fused(
        const unsigned long long* __restrict__ arena,
        const unsigned int* __restrict__ counters, float* __restrict__ out) {
    __shared__ __half2 acc[BH * WW * 2];   // [row][col][pol] {w,wt} = 40 KB
    __shared__ float ls[16];
    int b = blockIdx.x & 7;                // XCD-affinity
    int s = blockIdx.x >> 3;
    int tid = threadIdx.x;
    int r0 = s * BH;

    #pragma unroll
    for (int t = 0; t < 2; ++t) {
        uint4* az = (uint4*)acc;           // 2560 x uint4
        for (int i = tid; i < (BH * WW * 2) / 4; i += 1024)
            az[i] = make_uint4(0u, 0u, 0u, 0u);
        __syncthreads();

        unsigned int cnt = counters[(t * BB + b) * NSL + s];
        if (cnt > STRIDE) cnt = STRIDE;
        const ulonglong2* cell2 = (const ulonglong2*)(
            arena + (size_t)t * AE + (size_t)(b * NSL + s) * STRIDE);
        unsigned int n2 = (cnt + 1u) >> 1;
        for (unsigned int i2 = tid; i2 < n2; i2 += 1024) {
            ulonglong2 v = cell2[i2];
            #pragma unroll
            for (int j = 0; j < 2; ++j) {
                unsigned long long q = j ? v.y : v.x;
                if (2u * i2 + (unsigned int)j >= cnt) continue;
                float tw = (float)(unsigned int)(q & 0xFFFFu) * (1.0f / 65535.0f);
                int  pol = (int)((q >> 16) & 1u);
                float wx = (float)(unsigned int)((q >> 17) & 0x1FFFFFu) * (1.0f / 2048.0f) - 2.0f;
                float wy = (float)(unsigned int)((q >> 38) & 0xFFFFFu)  * (1.0f / 2048.0f) - 2.0f;
                float fy = floorf(wy), fx2 = floorf(wx);
                float ry = wy - fy,    rx = wx - fx2;
                int ity = (int)fy, ilx = (int)fx2;
                #pragma unroll
                for (int dy = 0; dy < 2; ++dy) {
                    int r = ity + dy;
                    if (r < r0 || r >= r0 + BH) continue;   // clip rows to slice
                    float wyw = dy ? ry : 1.0f - ry;
                    #pragma unroll
                    for (int dx = 0; dx < 2; ++dx) {
                        int ix = ilx + dx;
                        if (ix < 0 || ix >= WW) continue;
                        float wgt = wyw * (dx ? rx : 1.0f - rx);
                        int a = (((r - r0) * WW + ix) << 1) | pol;
                        unsafeAtomicAdd(&acc[a], __floats2half2_rn(wgt, wgt * tw));
                    }
                }
            }
        }
        __syncthreads();

        float sum = 0.0f;
        const uint2* av = (const uint2*)acc;   // 5120 x uint2
        for (int i = tid; i < (BH * WW * 2) / 2; i += 1024) {
            uint2 v = av[i];
            if (v.x) {
                float2 c = __half22float2(*(const __half2*)&v.x);
                float r = c.y * __builtin_amdgcn_rcpf(c.x + 1e-9f);
                sum += r * r;
            }
            if (v.y) {
                float2 c = __half22float2(*(const __half2*)&v.y);
                float r = c.y * __builtin_amdgcn_rcpf(c.x + 1e-9f);
                sum += r * r;
            }
        }
        #pragma unroll
        for (int off = 32; off > 0; off >>= 1)
            sum += __shfl_down(sum, off, 64);
        int lane = tid & 63, wid = tid >> 6;
        if (lane == 0) ls[wid] = sum;
        __syncthreads();
        if (tid == 0) {
            float tot = 0.0f;
            #pragma unroll
            for (int k = 0; k < 16; ++k) tot += ls[k];
            atomicAdd(out, tot);
        }
        __syncthreads();                   // protect acc/ls reuse across trefs
    }
}

extern "C" void kernel_launch(void* const* d_in, const int* in_sizes, int n_in,
                              void* d_out, int out_size, void* d_ws, size_t ws_size,
                              hipStream_t stream) {
    const float*  flow = (const float*)d_in[0];   // [B,2,H,W]
    const float4* ev   = (const float4*)d_in[1];  // [B,N,4]
    float* out = (float*)d_out;

    // ws: arena u64[2*AE] (35.4 MB) | fxy half2[B*HW] (9.83 MB) | counters
    unsigned long long* arena = (unsigned long long*)d_ws;
    __half2* fxy = (__half2*)((char*)d_ws + 2 * AE * sizeof(unsigned long long));
    unsigned int* counters = (unsigned int*)((char*)fxy +
                              (size_t)BB * HWSZ * sizeof(__half2));

    hipMemsetAsync(out, 0, sizeof(float), stream);
    hipMemsetAsync(counters, 0, 2 * BB * NSL * sizeof(unsigned int), stream);

    flow_prep<<<1024, 256, 0, stream>>>(flow, fxy, out);
    warp_place_dual<<<8 * BPB2, 256, 0, stream>>>(ev, fxy, counters, arena);
    slice_accum_fused<<<8 * NSL, 1024, 0, stream>>>(arena, counters, out);
}

// Round 11
// 102.980 us; speedup vs baseline: 1.4333x; 1.4082x over previous
//
#include <hip/hip_runtime.h>
#include <hip/hip_fp16.h>

#define BB 8
#define NN 200000
#define HH 480
#define WW 640
#define HWSZ (HH * WW)
#define BH 4                        // rows per slice
#define NSL (HH / BH)               // 120 slices
#define STRIDE 3584                 // u64 slots per (b,slice); mean ~2050
#define AE ((size_t)BB * NSL * STRIDE)   // arena u64 elements per tref

#define EPB2 1024
#define BPB2 ((NN + EPB2 - 1) / EPB2)    // 196

// LDS accumulator geometry (slice_accum): 6 rows (4 + 2 halo) x 2 pol x
// 642 cols (640 + 2 halo) u32 cells {w:16b lo, wt:16b hi}, scale 512.
// Two column-shifted copies for 8B-aligned u64 pair atomics.
#define ROWW   1284                 // u32 words per row (2 pol x 642)
#define CPYW   (6 * ROWW)           // 7704 words per copy
#define ACCW   (2 * CPYW)           // 15408 words = 61.6 KB

// ---------------------------------------------------------------------------
// K0: flow interleave (f32x2 -> half2) fused with Charbonnier smoothness.
// ---------------------------------------------------------------------------
__global__ void __launch_bounds__(256) flow_prep(
        const float* __restrict__ flow, __half2* __restrict__ fxy,
        float* __restrict__ out) {
    const int total = BB * HWSZ;
    float s = 0.0f;
    for (int i = blockIdx.x * 256 + threadIdx.x; i < total;
         i += gridDim.x * 256) {
        int b = i / HWSZ, pix = i % HWSZ;
        const float* fb = flow + (size_t)b * 2 * HWSZ;
        float f0 = fb[pix], f1 = fb[HWSZ + pix];
        fxy[i] = __floats2half2_rn(f0, f1);
        int w = pix % WW, h = pix / WW;
        if (h < HH - 1) {
            float d0 = f0 - fb[pix + WW];
            float d1 = f1 - fb[HWSZ + pix + WW];
            s += sqrtf(d0 * d0 + 1e-6f) + sqrtf(d1 * d1 + 1e-6f);
        }
        if (w < WW - 1) {
            float d0 = f0 - fb[pix + 1];
            float d1 = f1 - fb[HWSZ + pix + 1];
            s += sqrtf(d0 * d0 + 1e-6f) + sqrtf(d1 * d1 + 1e-6f);
        }
    }
    #pragma unroll
    for (int off = 32; off > 0; off >>= 1)
        s += __shfl_down(s, off, 64);
    __shared__ float ls[4];
    int lane = threadIdx.x & 63, wid = threadIdx.x >> 6;
    if (lane == 0) ls[wid] = s;
    __syncthreads();
    if (threadIdx.x == 0)
        atomicAdd(out, ls[0] + ls[1] + ls[2] + ls[3]);
}

// ---------------------------------------------------------------------------
// K1: warp each event for BOTH trefs; per-tref LDS hist; one global atomicAdd
// per touched (tref,slice) to reserve a range; 8B packed payloads (PROVEN R7
// encoding): [qy:20 @38][qx:21 @17][pol:1 @16][qt:16 @0], coords (v+2)*2048.
// Same payload goes to both buckets of a straddling event (absolute coords).
// ---------------------------------------------------------------------------
__global__ void __launch_bounds__(256) warp_place_dual(
        const float4* __restrict__ ev, const __half2* __restrict__ fxy,
        unsigned int* __restrict__ counters,
        unsigned long long* __restrict__ arena) {
    __shared__ unsigned int h[2][NSL];
    __shared__ unsigned int bases[2][NSL];
    int b     = blockIdx.x & 7;            // XCD-affinity: batch b -> XCD b
    int chunk = blockIdx.x >> 3;
    if (threadIdx.x < 2 * NSL) h[threadIdx.x / NSL][threadIdx.x % NSL] = 0;
    __syncthreads();

    const float4*  evb = ev  + (size_t)b * NN;
    const __half2* fb  = fxy + (size_t)b * HWSZ;
    int base = chunk * EPB2;

    unsigned long long pay[2][4];
    unsigned short code[2][4];             // 0 invalid; else (s0+1) | dual<<8
    #pragma unroll
    for (int k = 0; k < 4; ++k) {
        code[0][k] = 0; code[1][k] = 0;
        int e = base + k * 256 + threadIdx.x;
        if (e < NN) {
            float4 E = evb[e];
            int gpix = (int)(E.y * 640.0f + E.z);
            float2 f = __half22float2(fb[gpix]);
            unsigned int pol = (E.w < 0.0f) ? 1u : 0u;
            #pragma unroll
            for (int t = 0; t < 2; ++t) {
                float tref = (t == 0) ? 1.0f : 0.0f;
                float dt = tref - E.x;
                float wy = fmaf(dt * f.y, 640.0f, E.y);   // flow_scaling=640
                float wx = fmaf(dt * f.x, 640.0f, E.z);
                if (wx >= -1.0f && wx < 640.0f && wy >= -2.0f && wy < 481.0f) {
                    int ity = (int)floorf(wy);
                    int r1 = ity + 1;
                    bool v0 = (ity >= 0) && (ity < HH);
                    bool v1 = (r1  >= 0) && (r1  < HH);
                    int s0 = -1; bool dual = false;
                    if (v0) { s0 = ity >> 2; dual = v1 && ((r1 >> 2) != s0); }
                    else if (v1) s0 = r1 >> 2;
                    if (s0 >= 0) {
                        code[t][k] = (unsigned short)((s0 + 1) | (dual ? 0x200 : 0));
                        float tw = (t == 0) ? E.x : (1.0f - E.x);
                        unsigned int qy = (unsigned int)((wy + 2.0f) * 2048.0f);
                        unsigned int qx = (unsigned int)((wx + 2.0f) * 2048.0f);
                        unsigned int qt = (unsigned int)fmaf(tw, 65535.0f, 0.5f);
                        pay[t][k] = ((unsigned long long)qy << 38)
                                  | ((unsigned long long)qx << 17)
                                  | ((unsigned long long)pol << 16)
                                  | (unsigned long long)qt;
                        atomicAdd(&h[t][s0], 1u);
                        if (dual) atomicAdd(&h[t][s0 + 1], 1u);
                    }
                }
            }
        }
    }
    __syncthreads();
    if (threadIdx.x < 2 * NSL) {           // 240 < 256
        int t = threadIdx.x / NSL, s = threadIdx.x % NSL;
        unsigned int c = h[t][s];
        bases[t][s] = c ? atomicAdd(&counters[(t * BB + b) * NSL + s], c) : 0u;
        h[t][s] = 0;                       // reuse as within-block cursor
    }
    __syncthreads();
    #pragma unroll
    for (int t = 0; t < 2; ++t) {
        unsigned long long* at = arena + (size_t)t * AE + (size_t)b * NSL * STRIDE;
        #pragma unroll
        for (int k = 0; k < 4; ++k) {
            unsigned int c = code[t][k];
            if (c) {
                int s = (int)(c & 0x1ff) - 1;
                unsigned long long p = pay[t][k];
                unsigned int off = bases[t][s] + atomicAdd(&h[t][s], 1u);
                if (off < STRIDE) at[(size_t)s * STRIDE + off] = p;
                if (c & 0x200) {
                    off = bases[t][s + 1] + atomicAdd(&h[t][s + 1], 1u);
                    if (off < STRIDE) at[(size_t)(s + 1) * STRIDE + off] = p;
                }
            }
        }
    }
}

// ---------------------------------------------------------------------------
// K2: one block (1024 thr) per (b,slice); both trefs serial in-block.
// Integer fixed-point LDS accumulate: per entry TWO ds_add_u64 atomics, each
// covering two x-adjacent corners' packed {w:16b, wt:16b} (scale 512) cells.
// Branchless via halo rows/cols; two column-shifted copies give 8B alignment
// for any column parity. Fused ratio-square reduce, one atomic per bucket.
// LDS 61.6KB -> 2 blocks/CU (32 waves).
// ---------------------------------------------------------------------------
__global__ void __launch_bounds__(1024) slice_accum_fused(
        const unsigned long long* __restrict__ arena,
        const unsigned int* __restrict__ counters, float* __restrict__ out) {
    __shared__ unsigned int accw[ACCW];    // 61.6 KB, two copies
    __shared__ float ls[16];
    const int b = blockIdx.x & 7;          // XCD-affinity
    const int s = blockIdx.x >> 3;
    const int tid = threadIdx.x;
    const int r0 = s * BH;

    #pragma unroll
    for (int t = 0; t < 2; ++t) {
        uint4* az = (uint4*)accw;          // 3852 x uint4
        for (int i = tid; i < ACCW / 4; i += 1024)
            az[i] = make_uint4(0u, 0u, 0u, 0u);
        __syncthreads();

        unsigned int cnt = counters[(t * BB + b) * NSL + s];
        if (cnt > STRIDE) cnt = STRIDE;
        const ulonglong2* cell2 = (const ulonglong2*)(
            arena + (size_t)t * AE + (size_t)(b * NSL + s) * STRIDE);
        unsigned int n2 = (cnt + 1u) >> 1;
        for (unsigned int i2 = tid; i2 < n2; i2 += 1024) {
            ulonglong2 v = cell2[i2];
            #pragma unroll
            for (int j = 0; j < 2; ++j) {
                unsigned long long q = j ? v.y : v.x;
                if (2u * i2 + (unsigned int)j >= cnt) continue;
                unsigned int lo = (unsigned int)q, hi = (unsigned int)(q >> 32);
                int qt  = (int)(lo & 0xFFFFu);
                int pol = (int)((lo >> 16) & 1u);
                unsigned int qx = ((lo >> 17) | (hi << 15)) & 0x1FFFFFu;
                unsigned int qy = (hi >> 6) & 0xFFFFFu;
                int cc = (int)(qx >> 11) - 1;            // left-corner col +1: 0..640
                int rr = (int)(qy >> 11) - 1 - r0;       // floor-row rel +1: 0..4
                int rxi = (int)(qx & 2047u), ryi = (int)(qy & 2047u);
                int irx = 2048 - rxi, iry = 2048 - ryi;
                int w00 = (__mul24(iry, irx) + 4096) >> 13;  // scale 512
                int w01 = (__mul24(iry, rxi) + 4096) >> 13;
                int w10 = (__mul24(ryi, irx) + 4096) >> 13;
                int w11 = (__mul24(ryi, rxi) + 4096) >> 13;
                int t00 = (__mul24(w00, qt) + 32768) >> 16;
                int t01 = (__mul24(w01, qt) + 32768) >> 16;
                int t10 = (__mul24(w10, qt) + 32768) >> 16;
                int t11 = (__mul24(w11, qt) + 32768) >> 16;
                unsigned long long v0 =
                    ((unsigned long long)(unsigned int)(w01 | (t01 << 16)) << 32)
                    | (unsigned int)(w00 | (t00 << 16));
                unsigned long long v1 =
                    ((unsigned long long)(unsigned int)(w11 | (t11 << 16)) << 32)
                    | (unsigned int)(w10 | (t10 << 16));
                int sel = cc & 1;
                int idx = cc + sel + (sel ? CPYW : 0);   // copy B if odd start
                int a0  = rr * ROWW + pol * 642 + idx;
                unsigned long long* p0 = (unsigned long long*)&accw[a0];
                atomicAdd(p0, v0);                       // row rr   (ds_add_u64)
                atomicAdd(p0 + (ROWW / 2), v1);          // row rr+1 (offset imm)
            }
        }
        __syncthreads();

        // fused ratio reduce over real cells (rows 1..4, S-cols 1..640)
        float sum = 0.0f;
        for (int wi = tid; wi < CPYW; wi += 1024) {
            int row = wi / ROWW;
            if (row == 0 || row == 5) continue;          // halo rows
            int colw = wi - row * ROWW;
            int ci = (colw >= 642) ? colw - 642 : colw;  // col within pol-row
            if (ci == 0 || ci == 641) continue;          // halo cols
            unsigned int a  = accw[wi];
            unsigned int bb = accw[wi + 1 + CPYW];       // copy B partner
            unsigned int w  = (a & 0xFFFFu) + (bb & 0xFFFFu);
            if (!w) continue;
            unsigned int wt = (a >> 16) + (bb >> 16);
            float r = (float)wt * __builtin_amdgcn_rcpf((float)w);
            sum += r * r;
        }
        #pragma unroll
        for (int off = 32; off > 0; off >>= 1)
            sum += __shfl_down(sum, off, 64);
        int lane = tid & 63, wid = tid >> 6;
        if (lane == 0) ls[wid] = sum;
        __syncthreads();
        if (tid == 0) {
            float tot = 0.0f;
            #pragma unroll
            for (int k = 0; k < 16; ++k) tot += ls[k];
            atomicAdd(out, tot);
        }
        __syncthreads();                   // protect accw/ls reuse across trefs
    }
}

extern "C" void kernel_launch(void* const* d_in, const int* in_sizes, int n_in,
                              void* d_out, int out_size, void* d_ws, size_t ws_size,
                              hipStream_t stream) {
    const float*  flow = (const float*)d_in[0];   // [B,2,H,W]
    const float4* ev   = (const float4*)d_in[1];  // [B,N,4]
    float* out = (float*)d_out;

    // ws: arena u64[2*AE] (55.1 MB) | fxy half2[B*HW] (9.83 MB) | counters
    unsigned long long* arena = (unsigned long long*)d_ws;
    __half2* fxy = (__half2*)((char*)d_ws + 2 * AE * sizeof(unsigned long long));
    unsigned int* counters = (unsigned int*)((char*)fxy +
                              (size_t)BB * HWSZ * sizeof(__half2));

    hipMemsetAsync(out, 0, sizeof(float), stream);
    hipMemsetAsync(counters, 0, 2 * BB * NSL * sizeof(unsigned int), stream);

    flow_prep<<<1024, 256, 0, stream>>>(flow, fxy, out);
    warp_place_dual<<<8 * BPB2, 256, 0, stream>>>(ev, fxy, counters, arena);
    slice_accum_fused<<<8 * NSL, 1024, 0, stream>>>(arena, counters, out);
}

// Round 12
// 98.145 us; speedup vs baseline: 1.5039x; 1.0493x over previous
//
#include <hip/hip_runtime.h>
#include <hip/hip_fp16.h>

#define BB 8
#define NN 200000
#define HH 480
#define WW 640
#define HWSZ (HH * WW)
#define BH 4                        // rows per slice
#define NSL (HH / BH)               // 120 slices
#define STRIDE 3584                 // u64 slots per (b,slice); mean ~2050
#define AE ((size_t)BB * NSL * STRIDE)   // arena u64 elements per tref

#define EPB2 1024
#define BPB2 ((NN + EPB2 - 1) / EPB2)    // 196

// LDS accumulator geometry (slice_accum): 6 rows (4 + 2 halo) x 2 pol x
// 642 cols (640 + 2 halo) u32 cells {w:16b lo, wt:16b hi}, scale 512.
// Two column-shifted copies for 8B-aligned u64 pair atomics.
#define ROWW   1284                 // u32 words per row (2 pol x 642)
#define CPYW   (6 * ROWW)           // 7704 words per copy
#define ACCW   (2 * CPYW)           // 15408 words = 61.6 KB

// ---------------------------------------------------------------------------
// K0: flow interleave (f32x2 -> half2) fused with Charbonnier smoothness.
// ---------------------------------------------------------------------------
__global__ void __launch_bounds__(256) flow_prep(
        const float* __restrict__ flow, __half2* __restrict__ fxy,
        float* __restrict__ out) {
    const int total = BB * HWSZ;
    float s = 0.0f;
    for (int i = blockIdx.x * 256 + threadIdx.x; i < total;
         i += gridDim.x * 256) {
        int b = i / HWSZ, pix = i % HWSZ;
        const float* fb = flow + (size_t)b * 2 * HWSZ;
        float f0 = fb[pix], f1 = fb[HWSZ + pix];
        fxy[i] = __floats2half2_rn(f0, f1);
        int w = pix % WW, h = pix / WW;
        if (h < HH - 1) {
            float d0 = f0 - fb[pix + WW];
            float d1 = f1 - fb[HWSZ + pix + WW];
            s += sqrtf(d0 * d0 + 1e-6f) + sqrtf(d1 * d1 + 1e-6f);
        }
        if (w < WW - 1) {
            float d0 = f0 - fb[pix + 1];
            float d1 = f1 - fb[HWSZ + pix + 1];
            s += sqrtf(d0 * d0 + 1e-6f) + sqrtf(d1 * d1 + 1e-6f);
        }
    }
    #pragma unroll
    for (int off = 32; off > 0; off >>= 1)
        s += __shfl_down(s, off, 64);
    __shared__ float ls[4];
    int lane = threadIdx.x & 63, wid = threadIdx.x >> 6;
    if (lane == 0) ls[wid] = s;
    __syncthreads();
    if (threadIdx.x == 0)
        atomicAdd(out, ls[0] + ls[1] + ls[2] + ls[3]);
}

// ---------------------------------------------------------------------------
// K1: warp each event for BOTH trefs; flat 240-counter LDS hist; in-block
// counting sort into LDS staging; coalesced run-wise arena writes.
// payload (PROVEN R7 encoding): [qy:20 @38][qx:21 @17][pol:1 @16][qt:16 @0],
// coords (v+2)*2048. Straddlers replicated into both buckets (abs coords).
// ---------------------------------------------------------------------------
__global__ void __launch_bounds__(256) warp_place_dual(
        const float4* __restrict__ ev, const __half2* __restrict__ fxy,
        unsigned int* __restrict__ counters,
        unsigned long long* __restrict__ arena) {
    __shared__ unsigned int h[2 * NSL];        // counts -> cursor
    __shared__ unsigned int lbase[2 * NSL];    // local excl-scan bases
    __shared__ unsigned int gbase[2 * NSL];    // global reserved bases
    __shared__ unsigned int wsum[4];
    __shared__ unsigned int grand;
    __shared__ unsigned long long staged[2 * EPB2 * 2];  // 4096 x 8B = 32 KB
    __shared__ unsigned char sid[2 * EPB2 * 2];          // bucket id per entry
    int b     = blockIdx.x & 7;            // XCD-affinity: batch b -> XCD b
    int chunk = blockIdx.x >> 3;
    int tid   = threadIdx.x;
    if (tid < 2 * NSL) h[tid] = 0;
    __syncthreads();

    const float4*  evb = ev  + (size_t)b * NN;
    const __half2* fb  = fxy + (size_t)b * HWSZ;
    int base = chunk * EPB2;

    unsigned long long pay[2][4];
    unsigned short code[2][4];             // 0 invalid; else (c+1) | dual<<9
    #pragma unroll
    for (int k = 0; k < 4; ++k) {
        code[0][k] = 0; code[1][k] = 0;
        int e = base + k * 256 + tid;
        if (e < NN) {
            float4 E = evb[e];
            int gpix = (int)(E.y * 640.0f + E.z);
            float2 f = __half22float2(fb[gpix]);
            unsigned int pol = (E.w < 0.0f) ? 1u : 0u;
            #pragma unroll
            for (int t = 0; t < 2; ++t) {
                float tref = (t == 0) ? 1.0f : 0.0f;
                float dt = tref - E.x;
                float wy = fmaf(dt * f.y, 640.0f, E.y);   // flow_scaling=640
                float wx = fmaf(dt * f.x, 640.0f, E.z);
                if (wx >= -1.0f && wx < 640.0f && wy >= -2.0f && wy < 481.0f) {
                    int ity = (int)floorf(wy);
                    int r1 = ity + 1;
                    bool v0 = (ity >= 0) && (ity < HH);
                    bool v1 = (r1  >= 0) && (r1  < HH);
                    int s0 = -1; bool dual = false;
                    if (v0) { s0 = ity >> 2; dual = v1 && ((r1 >> 2) != s0); }
                    else if (v1) s0 = r1 >> 2;
                    if (s0 >= 0) {
                        int c = t * NSL + s0;
                        code[t][k] = (unsigned short)((c + 1) | (dual ? 0x400 : 0));
                        float tw = (t == 0) ? E.x : (1.0f - E.x);
                        unsigned int qy = (unsigned int)((wy + 2.0f) * 2048.0f);
                        unsigned int qx = (unsigned int)((wx + 2.0f) * 2048.0f);
                        unsigned int qt = (unsigned int)fmaf(tw, 65535.0f, 0.5f);
                        pay[t][k] = ((unsigned long long)qy << 38)
                                  | ((unsigned long long)qx << 17)
                                  | ((unsigned long long)pol << 16)
                                  | (unsigned long long)qt;
                        atomicAdd(&h[c], 1u);
                        if (dual) atomicAdd(&h[c + 1], 1u);
                    }
                }
            }
        }
    }
    __syncthreads();

    // exclusive scan of 240 counters; reserve global ranges
    {
        int lane = tid & 63, wid = tid >> 6;
        unsigned int val = (tid < 2 * NSL) ? h[tid] : 0u;
        unsigned int inc = val;
        #pragma unroll
        for (int off = 1; off < 64; off <<= 1) {
            unsigned int tv = __shfl_up(inc, off, 64);
            if (lane >= off) inc += tv;
        }
        if (lane == 63) wsum[wid] = inc;
        __syncthreads();
        if (tid == 0) {
            unsigned int a = 0;
            #pragma unroll
            for (int k = 0; k < 4; ++k) { unsigned int tmp = wsum[k]; wsum[k] = a; a += tmp; }
        }
        __syncthreads();
        if (tid < 2 * NSL) {
            unsigned int lb = wsum[wid] + inc - val;
            lbase[tid] = lb;
            if (tid == 2 * NSL - 1) grand = lb + val;
            int t = tid / NSL, s = tid % NSL;
            gbase[tid] = h[tid] ? atomicAdd(&counters[(t * BB + b) * NSL + s], h[tid]) : 0u;
            h[tid] = 0;                    // reuse as cursor
        }
    }
    __syncthreads();

    // place into LDS staging (counting sort)
    #pragma unroll
    for (int t = 0; t < 2; ++t) {
        #pragma unroll
        for (int k = 0; k < 4; ++k) {
            unsigned int cd = code[t][k];
            if (cd) {
                int c = (int)(cd & 0x3ff) - 1;
                unsigned int pos = lbase[c] + atomicAdd(&h[c], 1u);
                staged[pos] = pay[t][k];
                sid[pos] = (unsigned char)c;
                if (cd & 0x400) {
                    pos = lbase[c + 1] + atomicAdd(&h[c + 1], 1u);
                    staged[pos] = pay[t][k];
                    sid[pos] = (unsigned char)(c + 1);
                }
            }
        }
    }
    __syncthreads();

    // coalesced copy: consecutive entries of a bucket -> consecutive addrs
    unsigned int G = grand;
    for (unsigned int p = tid; p < G; p += 256) {
        int c = (int)sid[p];
        int t = (c >= NSL) ? 1 : 0;
        int s = c - t * NSL;
        unsigned int off = gbase[c] + (p - lbase[c]);
        if (off < STRIDE)
            arena[(size_t)t * AE + ((size_t)(b * NSL + s)) * STRIDE + off] = staged[p];
    }
}

// ---------------------------------------------------------------------------
// K2: one block (1024 thr) per (b,slice); both trefs serial in-block.
// Integer fixed-point LDS accumulate: per entry TWO ds_add_u64 atomics, each
// covering two x-adjacent corners' packed {w:16b, wt:16b} (scale 512) cells.
// Branchless via halo rows/cols; two column-shifted copies give 8B alignment
// for any column parity. Fused ratio-square reduce, one atomic per bucket.
// LDS 61.6KB -> 2 blocks/CU (32 waves). UNCHANGED from R10.
// ---------------------------------------------------------------------------
__global__ void __launch_bounds__(1024) slice_accum_fused(
        const unsigned long long* __restrict__ arena,
        const unsigned int* __restrict__ counters, float* __restrict__ out) {
    __shared__ unsigned int accw[ACCW];    // 61.6 KB, two copies
    __shared__ float ls[16];
    const int b = blockIdx.x & 7;          // XCD-affinity
    const int s = blockIdx.x >> 3;
    const int tid = threadIdx.x;
    const int r0 = s * BH;

    #pragma unroll
    for (int t = 0; t < 2; ++t) {
        uint4* az = (uint4*)accw;          // 3852 x uint4
        for (int i = tid; i < ACCW / 4; i += 1024)
            az[i] = make_uint4(0u, 0u, 0u, 0u);
        __syncthreads();

        unsigned int cnt = counters[(t * BB + b) * NSL + s];
        if (cnt > STRIDE) cnt = STRIDE;
        const ulonglong2* cell2 = (const ulonglong2*)(
            arena + (size_t)t * AE + (size_t)(b * NSL + s) * STRIDE);
        unsigned int n2 = (cnt + 1u) >> 1;
        for (unsigned int i2 = tid; i2 < n2; i2 += 1024) {
            ulonglong2 v = cell2[i2];
            #pragma unroll
            for (int j = 0; j < 2; ++j) {
                unsigned long long q = j ? v.y : v.x;
                if (2u * i2 + (unsigned int)j >= cnt) continue;
                unsigned int lo = (unsigned int)q, hi = (unsigned int)(q >> 32);
                int qt  = (int)(lo & 0xFFFFu);
                int pol = (int)((lo >> 16) & 1u);
                unsigned int qx = ((lo >> 17) | (hi << 15)) & 0x1FFFFFu;
                unsigned int qy = (hi >> 6) & 0xFFFFFu;
                int cc = (int)(qx >> 11) - 1;            // left-corner col +1: 0..640
                int rr = (int)(qy >> 11) - 1 - r0;       // floor-row rel +1: 0..4
                int rxi = (int)(qx & 2047u), ryi = (int)(qy & 2047u);
                int irx = 2048 - rxi, iry = 2048 - ryi;
                int w00 = (__mul24(iry, irx) + 4096) >> 13;  // scale 512
                int w01 = (__mul24(iry, rxi) + 4096) >> 13;
                int w10 = (__mul24(ryi, irx) + 4096) >> 13;
                int w11 = (__mul24(ryi, rxi) + 4096) >> 13;
                int t00 = (__mul24(w00, qt) + 32768) >> 16;
                int t01 = (__mul24(w01, qt) + 32768) >> 16;
                int t10 = (__mul24(w10, qt) + 32768) >> 16;
                int t11 = (__mul24(w11, qt) + 32768) >> 16;
                unsigned long long v0 =
                    ((unsigned long long)(unsigned int)(w01 | (t01 << 16)) << 32)
                    | (unsigned int)(w00 | (t00 << 16));
                unsigned long long v1 =
                    ((unsigned long long)(unsigned int)(w11 | (t11 << 16)) << 32)
                    | (unsigned int)(w10 | (t10 << 16));
                int sel = cc & 1;
                int idx = cc + sel + (sel ? CPYW : 0);   // copy B if odd start
                int a0  = rr * ROWW + pol * 642 + idx;
                unsigned long long* p0 = (unsigned long long*)&accw[a0];
                atomicAdd(p0, v0);                       // row rr   (ds_add_u64)
                atomicAdd(p0 + (ROWW / 2), v1);          // row rr+1 (offset imm)
            }
        }
        __syncthreads();

        // fused ratio reduce over real cells (rows 1..4, S-cols 1..640)
        float sum = 0.0f;
        for (int wi = tid; wi < CPYW; wi += 1024) {
            int row = wi / ROWW;
            if (row == 0 || row == 5) continue;          // halo rows
            int colw = wi - row * ROWW;
            int ci = (colw >= 642) ? colw - 642 : colw;  // col within pol-row
            if (ci == 0 || ci == 641) continue;          // halo cols
            unsigned int a  = accw[wi];
            unsigned int bb = accw[wi + 1 + CPYW];       // copy B partner
            unsigned int w  = (a & 0xFFFFu) + (bb & 0xFFFFu);
            if (!w) continue;
            unsigned int wt = (a >> 16) + (bb >> 16);
            float r = (float)wt * __builtin_amdgcn_rcpf((float)w);
            sum += r * r;
        }
        #pragma unroll
        for (int off = 32; off > 0; off >>= 1)
            sum += __shfl_down(sum, off, 64);
        int lane = tid & 63, wid = tid >> 6;
        if (lane == 0) ls[wid] = sum;
        __syncthreads();
        if (tid == 0) {
            float tot = 0.0f;
            #pragma unroll
            for (int k = 0; k < 16; ++k) tot += ls[k];
            atomicAdd(out, tot);
        }
        __syncthreads();                   // protect accw/ls reuse across trefs
    }
}

extern "C" void kernel_launch(void* const* d_in, const int* in_sizes, int n_in,
                              void* d_out, int out_size, void* d_ws, size_t ws_size,
                              hipStream_t stream) {
    const float*  flow = (const float*)d_in[0];   // [B,2,H,W]
    const float4* ev   = (const float4*)d_in[1];  // [B,N,4]
    float* out = (float*)d_out;

    // ws: arena u64[2*AE] (55.1 MB) | fxy half2[B*HW] (9.83 MB) | counters
    unsigned long long* arena = (unsigned long long*)d_ws;
    __half2* fxy = (__half2*)((char*)d_ws + 2 * AE * sizeof(unsigned long long));
    unsigned int* counters = (unsigned int*)((char*)fxy +
                              (size_t)BB * HWSZ * sizeof(__half2));

    hipMemsetAsync(out, 0, sizeof(float), stream);
    hipMemsetAsync(counters, 0, 2 * BB * NSL * sizeof(unsigned int), stream);

    flow_prep<<<1024, 256, 0, stream>>>(flow, fxy, out);
    warp_place_dual<<<8 * BPB2, 256, 0, stream>>>(ev, fxy, counters, arena);
    slice_accum_fused<<<8 * NSL, 1024, 0, stream>>>(arena, counters, out);
}